// Round 4
// baseline (40827.026 us; speedup 1.0000x reference)
//
#include <hip/hip_runtime.h>
#include <stdint.h>

#define TT 16384
#define DH 512
#define KK 128
#define SENT 0xAAAAAAAAu
#define CROWS 32
#define NCHUNK (TT / CROWS)   // 512
#define NPROJ 112

// Large per-launch state in device globals (d_ws stays at the proven 64 MB:
// H0 + Xp0). g_H1u is sentinel-filled by init_kernel every launch.
__device__ uint32_t g_H1u[(size_t)TT * DH];   // layer-1 output (data-as-flag)
__device__ float    g_Xp1[(size_t)TT * DH];   // layer-1 input projection
__device__ uint32_t g_flagXp[2][NCHUNK];      // Xp chunk-ready flags (1 = ready)

static __device__ __forceinline__ uint32_t aload(const uint32_t* p) {
    return __hip_atomic_load(p, __ATOMIC_RELAXED, __HIP_MEMORY_SCOPE_AGENT);
}
static __device__ __forceinline__ void astore(uint32_t* p, uint32_t v) {
    __hip_atomic_store(p, v, __ATOMIC_RELAXED, __HIP_MEMORY_SCOPE_AGENT);
}

__global__ void init_kernel() {
    const size_t gtid = (size_t)blockIdx.x * blockDim.x + threadIdx.x;
    const size_t n = (size_t)TT * DH;
    const size_t stride = (size_t)gridDim.x * blockDim.x;
    for (size_t i = gtid; i < n; i += stride) g_H1u[i] = SENT;
    if (gtid < 2 * NCHUNK) (&g_flagXp[0][0])[gtid] = 0u;
}

union __align__(16) SMem {
    struct { float inT[DH * 36]; float wt[32 * 516]; } proj;  // 139776 B
    struct { float st[8][8][68]; } scan;                      // 17408 B (per-wave rows)
};

// ---------------- projector: 32-row chunk GEMM  dst = src @ W (512 thr) ------
// srcMode 0: plain loads (X). srcMode 1: per-word sentinel poll (H0, live).
// R2-style mapping: rg=tid>>7 (rows 8rg..8rg+7), cg=tid&127 (cols 4cg..4cg+3).
static __device__ void proj_chunk(SMem& sm, const float* __restrict__ W,
                                  const float* __restrict__ src, int srcMode,
                                  float* __restrict__ dst, uint32_t* flag, int t0)
{
    const int tid = threadIdx.x;
    #pragma unroll
    for (int i = 0; i < 32; ++i) {
        int idx = tid + 512 * i;           // 0..16383
        int row = idx >> 9;
        int col = idx & 511;
        float v;
        if (srcMode == 0) {
            v = src[(size_t)t0 * DH + idx];
        } else {
            const uint32_t* p = (const uint32_t*)src + (size_t)t0 * DH + idx;
            uint32_t u;
            while ((u = aload(p)) == SENT) __builtin_amdgcn_s_sleep(1);
            v = __uint_as_float(u);
        }
        sm.proj.inT[col * 36 + row] = v;
    }
    __syncthreads();

    const int rg = tid >> 7;     // 0..3 -> rows 8rg..8rg+7
    const int cg = tid & 127;    // cols 4cg..4cg+3
    float acc[8][4];
    #pragma unroll
    for (int i = 0; i < 8; ++i)
        #pragma unroll
        for (int j = 0; j < 4; ++j) acc[i][j] = 0.f;

    for (int kt = 0; kt < 16; ++kt) {
        const int k0 = kt * 32;
        #pragma unroll
        for (int i = 0; i < 8; ++i) {               // stage 32x512 W tile
            int f4 = tid + 512 * i;                 // 0..4095 float4s
            int wr = f4 >> 7;
            int wc = (f4 & 127) << 2;
            *(float4*)&sm.proj.wt[wr * 516 + wc] =
                *(const float4*)&W[(size_t)(k0 + wr) * DH + wc];
        }
        __syncthreads();
        #pragma unroll 4
        for (int kk = 0; kk < 32; ++kk) {
            float4 a0 = *(const float4*)&sm.proj.inT[(k0 + kk) * 36 + (rg << 3)];
            float4 a1 = *(const float4*)&sm.proj.inT[(k0 + kk) * 36 + (rg << 3) + 4];
            float4 w  = *(const float4*)&sm.proj.wt[kk * 516 + (cg << 2)];
            float av[8] = {a0.x, a0.y, a0.z, a0.w, a1.x, a1.y, a1.z, a1.w};
            float wv[4] = {w.x, w.y, w.z, w.w};
            #pragma unroll
            for (int i = 0; i < 8; ++i)
                #pragma unroll
                for (int j = 0; j < 4; ++j) acc[i][j] += av[i] * wv[j];
        }
        __syncthreads();
    }
    #pragma unroll
    for (int i = 0; i < 8; ++i)
        #pragma unroll
        for (int j = 0; j < 4; ++j)
            astore((uint32_t*)&dst[(size_t)(t0 + (rg << 3) + i) * DH + (cg << 2) + j],
                   __float_as_uint(acc[i][j]));
    __threadfence();
    __syncthreads();
    if (tid == 0)
        __hip_atomic_store(flag, 1u, __ATOMIC_RELEASE, __HIP_MEMORY_SCOPE_AGENT);
}

// ---------------- fused persistent kernel (512 threads/block) ----------------
// Blocks 0..15: scan role, layer = b&1, blk = b>>1 (8 blocks x 64 cols each).
// Within a scan block: 8 fully independent waves, each owning 8 columns.
// Blocks 16..127: projectors (Xp0 from X; Xp1 from live-polled H0).
__global__ __launch_bounds__(512, 1)
void fused(const float* __restrict__ X,
           const float* __restrict__ Wx0, const float* __restrict__ Wh0,
           const float* __restrict__ bh0, const float* __restrict__ h00,
           const float* __restrict__ Wx1, const float* __restrict__ Wh1,
           const float* __restrict__ bh1, const float* __restrict__ h01,
           float* H0r, float* Xp0)
{
    __shared__ SMem sm;
    const int bIdx = blockIdx.x;
    const int tid = threadIdx.x;

    if (bIdx < 16) {
        // ================= scan role =================
        const int L    = bIdx & 1;
        const int blk  = bIdx >> 1;          // 0..7
        const int w    = tid >> 6;           // wave 0..7
        const int lane = tid & 63;
        const int seg  = lane >> 3;          // input segment (64 inputs)
        const int m    = lane & 7;
        const int col  = (blk << 6) + (w << 3) + m;   // wave owns 8 cols

        const float* Wh  = L ? Wh1 : Wh0;
        const float* bhv = L ? bh1 : bh0;
        const float* h0v = L ? h01 : h00;
        uint32_t* HfulU  = L ? g_H1u : (uint32_t*)H0r;
        const uint32_t* HprevU = HfulU;
        const float* Xp  = L ? g_Xp1 : Xp0;
        uint32_t* flagXp = g_flagXp[L];

        // 64 weight VGPRs: Wh[64*seg + j][col]
        float wh[64];
        #pragma unroll
        for (int j = 0; j < 64; ++j)
            wh[j] = Wh[(size_t)((seg << 6) + j) * DH + col];
        const float bias = bhv[col];

        float* myseg = &sm.scan.st[w][seg][0];   // wave-private, bank-safe

        float xp_cur = 0.f;
        int curCh = 0;
        if (seg == 0) {
            while (__hip_atomic_load(&flagXp[0], __ATOMIC_ACQUIRE,
                                     __HIP_MEMORY_SCOPE_AGENT) != 1u)
                __builtin_amdgcn_s_sleep(1);
            xp_cur = Xp[col];
        }

        for (int t = 0; t < TT; ++t) {
            // ---- obtain my 8 h-words (stride-8 within my segment) ----
            uint32_t u[8];
            if (t == 0) {
                #pragma unroll
                for (int j = 0; j < 8; ++j)
                    u[j] = __float_as_uint(h0v[(seg << 6) + m + (j << 3)]);
            } else {
                const uint32_t* base = HprevU + (size_t)(t - 1) * DH + (seg << 6) + m;
                #pragma unroll
                for (int j = 0; j < 8; ++j) u[j] = aload(base + (j << 3));
                for (;;) {
                    uint32_t miss = 0;
                    #pragma unroll
                    for (int j = 0; j < 8; ++j) miss |= (u[j] == SENT);
                    if (!miss) break;
                    #pragma unroll
                    for (int j = 0; j < 8; ++j)
                        if (u[j] == SENT) u[j] = aload(base + (j << 3));
                }
            }
            // ---- intra-wave exchange via wave-private LDS (lockstep, no barrier;
            //      same idiom HW-verified correct in R3) ----
            #pragma unroll
            for (int j = 0; j < 8; ++j)
                myseg[m + (j << 3)] = __uint_as_float(u[j]);

            float acc = 0.f;
            const float4* h4 = (const float4*)myseg;
            #pragma unroll
            for (int r = 0; r < 16; ++r) {
                float4 hv = h4[r];
                acc += wh[4*r+0]*hv.x + wh[4*r+1]*hv.y
                     + wh[4*r+2]*hv.z + wh[4*r+3]*hv.w;
            }
            if (seg == 0) acc += bias + xp_cur;     // added exactly once
            // in-wave butterfly over the 8 segments (col preserved by xor 8/16/32)
            acc += __shfl_xor(acc, 8, 64);
            acc += __shfl_xor(acc, 16, 64);
            acc += __shfl_xor(acc, 32, 64);
            float v = fmaxf(acc, 0.f);

            if (seg == 0) {
                astore(&HfulU[(size_t)t * DH + col], __float_as_uint(v));
                if (t + 1 < TT) {                   // xp prefetch in the store shadow
                    const int ch = (t + 1) >> 5;
                    if (ch != curCh) {
                        while (__hip_atomic_load(&flagXp[ch], __ATOMIC_ACQUIRE,
                                                 __HIP_MEMORY_SCOPE_AGENT) != 1u) {}
                        curCh = ch;
                    }
                    xp_cur = __uint_as_float(
                        aload((const uint32_t*)&Xp[(size_t)(t + 1) * DH + col]));
                }
            }
        }
    } else {
        // ================= projector role =================
        const int pi = bIdx - 16;             // 0..111
        for (int cc = pi; cc < NCHUNK; cc += NPROJ) {
            proj_chunk(sm, Wx0, X,   0, Xp0,   &g_flagXp[0][cc], cc * CROWS);
            proj_chunk(sm, Wx1, H0r, 1, g_Xp1, &g_flagXp[1][cc], cc * CROWS);
        }
    }
}

// out[t][k] = dot(H1[t], W_log[k]) + b_log[k].  Block = 8 timesteps x 128 k.
__global__ __launch_bounds__(128, 1)
void logits_kernel(const float* __restrict__ Wl, const float* __restrict__ bl,
                   float* __restrict__ out)
{
    const float* H1 = (const float*)g_H1u;
    const int t0 = blockIdx.x * 8;
    const int k = threadIdx.x;

    __shared__ __align__(16) float hs[8 * DH];
    for (int idx = k; idx < 8 * DH / 4; idx += 128)
        ((float4*)hs)[idx] = ((const float4*)&H1[(size_t)t0 * DH])[idx];
    __syncthreads();

    float acc[8];
    const float bk = bl[k];
    #pragma unroll
    for (int r = 0; r < 8; ++r) acc[r] = bk;

    const float4* w4 = (const float4*)&Wl[(size_t)k * DH];
    for (int j = 0; j < DH / 4; ++j) {
        float4 w = w4[j];
        #pragma unroll
        for (int r = 0; r < 8; ++r) {
            float4 h = ((const float4*)&hs[r * DH])[j];
            acc[r] += w.x * h.x + w.y * h.y + w.z * h.z + w.w * h.w;
        }
    }
    #pragma unroll
    for (int r = 0; r < 8; ++r) out[(size_t)(t0 + r) * KK + k] = acc[r];
}

extern "C" void kernel_launch(void* const* d_in, const int* in_sizes, int n_in,
                              void* d_out, int out_size, void* d_ws, size_t ws_size,
                              hipStream_t stream)
{
    const float* X   = (const float*)d_in[0];
    const float* Wx0 = (const float*)d_in[1];
    const float* Wh0 = (const float*)d_in[2];
    const float* bh0 = (const float*)d_in[3];
    const float* h00 = (const float*)d_in[4];
    const float* Wx1 = (const float*)d_in[5];
    const float* Wh1 = (const float*)d_in[6];
    const float* bh1 = (const float*)d_in[7];
    const float* h01 = (const float*)d_in[8];
    const float* Wl  = (const float*)d_in[9];
    const float* bl  = (const float*)d_in[10];
    float* out = (float*)d_out;

    float* H0r = (float*)d_ws;                  // layer-0 H, data-as-flag (sentinel)
    float* Xp0 = H0r + (size_t)TT * DH;         // layer-0 input projection

    // H0 region must start at sentinel (harness poisons d_ws; defensive).
    hipMemsetAsync(d_ws, 0xAA, (size_t)TT * DH * sizeof(float), stream);
    hipLaunchKernelGGL(init_kernel, dim3(1024), dim3(256), 0, stream);
    hipLaunchKernelGGL(fused, dim3(16 + NPROJ), dim3(512), 0, stream,
                       X, Wx0, Wh0, bh0, h00, Wx1, Wh1, bh1, h01, H0r, Xp0);
    hipLaunchKernelGGL(logits_kernel, dim3(TT / 8), dim3(128), 0, stream,
                       Wl, bl, out);
}

// Round 5
// 22424.907 us; speedup vs baseline: 1.8206x; 1.8206x over previous
//
#include <hip/hip_runtime.h>
#include <stdint.h>

#define TT 16384
#define DH 512
#define KK 128
#define SENT 0xAAAAAAAAu
#define CROWS 32
#define NCHUNK (TT / CROWS)   // 512
#define NPROJ 112
#define RSLOT 16

// Device-global state. Ring + flags re-inited by init_kernel every launch.
// g_H1u / g_Xp1 are fully (re)written before any read each launch.
__device__ uint32_t g_ring[2][RSLOT][DH];     // 64 KB parity-tagged h rings (IC-hot)
__device__ uint32_t g_flagXp[2][NCHUNK];      // Xp chunk-ready flags (1 = ready)
__device__ uint32_t g_H1u[(size_t)TT * DH];   // layer-1 H (read only after fused ends)
__device__ float    g_Xp1[(size_t)TT * DH];   // layer-1 input projection

static __device__ __forceinline__ uint32_t aload(const uint32_t* p) {
    return __hip_atomic_load(p, __ATOMIC_RELAXED, __HIP_MEMORY_SCOPE_AGENT);
}
static __device__ __forceinline__ void astore(uint32_t* p, uint32_t v) {
    __hip_atomic_store(p, v, __ATOMIC_RELAXED, __HIP_MEMORY_SCOPE_AGENT);
}

__global__ void init_kernel() {
    const int tid = threadIdx.x + blockIdx.x * 1024;
    uint32_t* r = &g_ring[0][0][0];
    if (tid < 2 * RSLOT * DH) r[tid] = SENT;            // bit31=1 -> parity 1, spins t=1..16
    if (tid < 2 * NCHUNK) (&g_flagXp[0][0])[tid] = 0u;
}

union __align__(16) SMem {
    struct { float inT[DH * 36]; float wt[32 * 516]; } proj;  // 139776 B
    struct { float h[2][8][68]; } scan;                       // 4352 B, parity dbuf
};

// ---------------- projector: 32-row chunk GEMM  dst = src @ W (512 thr) ------
// srcMode 0: plain loads (X). srcMode 1: per-word sentinel poll (H0, live).
static __device__ void proj_chunk(SMem& sm, const float* __restrict__ W,
                                  const float* __restrict__ src, int srcMode,
                                  float* __restrict__ dst, uint32_t* flag, int t0)
{
    const int tid = threadIdx.x;
    #pragma unroll
    for (int i = 0; i < 32; ++i) {
        int idx = tid + 512 * i;           // 0..16383
        int row = idx >> 9;
        int col = idx & 511;
        float v;
        if (srcMode == 0) {
            v = src[(size_t)t0 * DH + idx];
        } else {
            const uint32_t* p = (const uint32_t*)src + (size_t)t0 * DH + idx;
            uint32_t u;
            while ((u = aload(p)) == SENT) __builtin_amdgcn_s_sleep(1);
            v = __uint_as_float(u);
        }
        sm.proj.inT[col * 36 + row] = v;
    }
    __syncthreads();

    const int rg = tid >> 7;     // rows 8rg..8rg+7
    const int cg = tid & 127;    // cols 4cg..4cg+3
    float acc[8][4];
    #pragma unroll
    for (int i = 0; i < 8; ++i)
        #pragma unroll
        for (int j = 0; j < 4; ++j) acc[i][j] = 0.f;

    for (int kt = 0; kt < 16; ++kt) {
        const int k0 = kt * 32;
        #pragma unroll
        for (int i = 0; i < 8; ++i) {               // stage 32x512 W tile
            int f4 = tid + 512 * i;                 // 0..4095 float4s
            int wr = f4 >> 7;
            int wc = (f4 & 127) << 2;
            *(float4*)&sm.proj.wt[wr * 516 + wc] =
                *(const float4*)&W[(size_t)(k0 + wr) * DH + wc];
        }
        __syncthreads();
        #pragma unroll 4
        for (int kk = 0; kk < 32; ++kk) {
            float4 a0 = *(const float4*)&sm.proj.inT[(k0 + kk) * 36 + (rg << 3)];
            float4 a1 = *(const float4*)&sm.proj.inT[(k0 + kk) * 36 + (rg << 3) + 4];
            float4 w  = *(const float4*)&sm.proj.wt[kk * 516 + (cg << 2)];
            float av[8] = {a0.x, a0.y, a0.z, a0.w, a1.x, a1.y, a1.z, a1.w};
            float wv[4] = {w.x, w.y, w.z, w.w};
            #pragma unroll
            for (int i = 0; i < 8; ++i)
                #pragma unroll
                for (int j = 0; j < 4; ++j) acc[i][j] += av[i] * wv[j];
        }
        __syncthreads();
    }
    #pragma unroll
    for (int i = 0; i < 8; ++i)
        #pragma unroll
        for (int j = 0; j < 4; ++j)
            astore((uint32_t*)&dst[(size_t)(t0 + (rg << 3) + i) * DH + (cg << 2) + j],
                   __float_as_uint(acc[i][j]));
    __threadfence();
    __syncthreads();
    if (tid == 0)
        __hip_atomic_store(flag, 1u, __ATOMIC_RELEASE, __HIP_MEMORY_SCOPE_AGENT);
}

// ---------------- fused persistent kernel (512 threads/block) ----------------
// Blocks 0..15: scan role, layer = b&1, chunk-id b>>1 (8 blocks x 64 cols).
// 8 symmetric waves: wave owns 8 cols; lane (seg,m) handles 64-input segment seg
// of col w*8+m; butterfly over seg. Waves 0..6 poll one remote 64-word ring
// chunk (1 word/lane). One barrier/step; LDS h-buffer parity-double-buffered.
// Blocks 16..127: projectors (Xp0 from X; Xp1 from live-polled H0).
__global__ __launch_bounds__(512, 1)
void fused(const float* __restrict__ X,
           const float* __restrict__ Wx0, const float* __restrict__ Wh0,
           const float* __restrict__ bh0, const float* __restrict__ h00,
           const float* __restrict__ Wx1, const float* __restrict__ Wh1,
           const float* __restrict__ bh1, const float* __restrict__ h01,
           float* H0r, float* Xp0)
{
    __shared__ SMem sm;
    const int bIdx = blockIdx.x;
    const int tid = threadIdx.x;

    if (bIdx < 16) {
        // ================= scan role =================
        const int L    = bIdx & 1;
        const int b    = bIdx >> 1;          // this block's chunk id, cols [64b,64b+64)
        const int w    = tid >> 6;           // wave 0..7
        const int lane = tid & 63;
        const int seg  = lane >> 3;          // input segment (64 inputs)
        const int m    = lane & 7;
        const int col  = (b << 6) + (w << 3) + m;
        const int pc   = (w < b) ? w : w + 1;   // polled remote chunk (waves 0..6)

        const float* Wh  = L ? Wh1 : Wh0;
        const float* bhv = L ? bh1 : bh0;
        const float* h0v = L ? h01 : h00;
        uint32_t* HfulU  = L ? g_H1u : (uint32_t*)H0r;
        const float* Xp  = L ? g_Xp1 : Xp0;
        uint32_t* flagXp = g_flagXp[L];
        uint32_t (*ring)[DH] = g_ring[L];

        // 64 weight VGPRs: Wh[64*seg + j][col]
        float wh[64];
        #pragma unroll
        for (int j = 0; j < 64; ++j)
            wh[j] = Wh[(size_t)((seg << 6) + j) * DH + col];
        const float bias = bhv[col];

        float v = h0v[col];                  // "previous" value entering step 0
        float xp_cur = 0.f;
        int curCh = 0;
        if (seg == 0) {
            while (__hip_atomic_load(&flagXp[0], __ATOMIC_ACQUIRE,
                                     __HIP_MEMORY_SCOPE_AGENT) != 1u) {}
            xp_cur = Xp[col];
        }

        for (int t = 0; t < TT; ++t) {
            const int pb = t & 1;
            // self-chunk publish (from registers; never touches the fabric)
            if (seg == 0) sm.scan.h[pb][b][(w << 3) + m] = v;
            // remote chunk poll: 1 word per lane, hot ring line
            if (w < 7) {
                float hv;
                if (t == 0) {
                    hv = h0v[(pc << 6) + lane];
                } else {
                    const uint32_t par = (uint32_t)((t - 1) >> 4) & 1u;
                    const uint32_t* p = &ring[(t - 1) & 15][(pc << 6) + lane];
                    uint32_t u;
                    do { u = aload(p); } while ((u >> 31) != par);
                    hv = __uint_as_float(u & 0x7fffffffu);
                }
                sm.scan.h[pb][pc][lane] = hv;
            }
            __syncthreads();                 // h[pb] fully staged

            float acc = 0.f;
            const float4* h4 = (const float4*)&sm.scan.h[pb][seg][0];
            #pragma unroll
            for (int r = 0; r < 16; ++r) {   // 8-seg spread + 8-lane broadcast: conflict-free
                float4 hv = h4[r];
                acc += wh[4*r+0]*hv.x + wh[4*r+1]*hv.y
                     + wh[4*r+2]*hv.z + wh[4*r+3]*hv.w;
            }
            if (seg == 0) acc += bias + xp_cur;          // added exactly once
            acc += __shfl_xor(acc, 8, 64);               // reduce over seg bits
            acc += __shfl_xor(acc, 16, 64);
            acc += __shfl_xor(acc, 32, 64);
            v = fmaxf(acc, 0.f);

            if (seg == 0) {
                const uint32_t hb = __float_as_uint(v);
                // ring store FIRST: remote pollers' critical path
                astore(&ring[t & 15][col],
                       hb | (((uint32_t)(t >> 4) & 1u) << 31));
                astore(HfulU + (size_t)t * DH + col, hb);
                if (t + 1 < TT) {            // xp prefetch in the poll shadow
                    const int ch = (t + 1) >> 5;
                    if (ch != curCh) {
                        while (__hip_atomic_load(&flagXp[ch], __ATOMIC_ACQUIRE,
                                                 __HIP_MEMORY_SCOPE_AGENT) != 1u) {}
                        curCh = ch;
                    }
                    xp_cur = __uint_as_float(
                        aload((const uint32_t*)&Xp[(size_t)(t + 1) * DH + col]));
                }
            }
        }
    } else {
        // ================= projector role =================
        const int pi = bIdx - 16;             // 0..111
        for (int cc = pi; cc < NCHUNK; cc += NPROJ) {
            proj_chunk(sm, Wx0, X,   0, Xp0,   &g_flagXp[0][cc], cc * CROWS);
            proj_chunk(sm, Wx1, H0r, 1, g_Xp1, &g_flagXp[1][cc], cc * CROWS);
        }
    }
}

// out[t][k] = dot(H1[t], W_log[k]) + b_log[k].  Block = 8 timesteps x 128 k.
__global__ __launch_bounds__(128, 1)
void logits_kernel(const float* __restrict__ Wl, const float* __restrict__ bl,
                   float* __restrict__ out)
{
    const float* H1 = (const float*)g_H1u;
    const int t0 = blockIdx.x * 8;
    const int k = threadIdx.x;

    __shared__ __align__(16) float hs[8 * DH];
    for (int idx = k; idx < 8 * DH / 4; idx += 128)
        ((float4*)hs)[idx] = ((const float4*)&H1[(size_t)t0 * DH])[idx];
    __syncthreads();

    float acc[8];
    const float bk = bl[k];
    #pragma unroll
    for (int r = 0; r < 8; ++r) acc[r] = bk;

    const float4* w4 = (const float4*)&Wl[(size_t)k * DH];
    for (int j = 0; j < DH / 4; ++j) {
        float4 w = w4[j];
        #pragma unroll
        for (int r = 0; r < 8; ++r) {
            float4 h = ((const float4*)&hs[r * DH])[j];
            acc[r] += w.x * h.x + w.y * h.y + w.z * h.z + w.w * h.w;
        }
    }
    #pragma unroll
    for (int r = 0; r < 8; ++r) out[(size_t)(t0 + r) * KK + k] = acc[r];
}

extern "C" void kernel_launch(void* const* d_in, const int* in_sizes, int n_in,
                              void* d_out, int out_size, void* d_ws, size_t ws_size,
                              hipStream_t stream)
{
    const float* X   = (const float*)d_in[0];
    const float* Wx0 = (const float*)d_in[1];
    const float* Wh0 = (const float*)d_in[2];
    const float* bh0 = (const float*)d_in[3];
    const float* h00 = (const float*)d_in[4];
    const float* Wx1 = (const float*)d_in[5];
    const float* Wh1 = (const float*)d_in[6];
    const float* bh1 = (const float*)d_in[7];
    const float* h01 = (const float*)d_in[8];
    const float* Wl  = (const float*)d_in[9];
    const float* bl  = (const float*)d_in[10];
    float* out = (float*)d_out;

    float* H0r = (float*)d_ws;                  // layer-0 H (sentinel-inited, polled by projector)
    float* Xp0 = H0r + (size_t)TT * DH;         // layer-0 input projection (flag-gated)

    // H0 must start at sentinel (harness poisons d_ws; defensive & capture-legal).
    hipMemsetAsync(d_ws, 0xAA, (size_t)TT * DH * sizeof(float), stream);
    hipLaunchKernelGGL(init_kernel, dim3(17), dim3(1024), 0, stream);
    hipLaunchKernelGGL(fused, dim3(16 + NPROJ), dim3(512), 0, stream,
                       X, Wx0, Wh0, bh0, h00, Wx1, Wh1, bh1, h01, H0r, Xp0);
    hipLaunchKernelGGL(logits_kernel, dim3(TT / 8), dim3(128), 0, stream,
                       Wl, bl, out);
}